// Round 2
// baseline (12987.741 us; speedup 1.0000x reference)
//
#include <hip/hip_runtime.h>
#include <stdint.h>

// Teacher-forced LSTM, B=64 T=512 D=H=1024.
// gates = m.(h@Wx^T) + (1-m).(x@Wx^T) + h@Wh^T + bx + bh
// Persistent: 128 blocks x 512 thr; block owns 8 hidden units (32 gate rows).
// Weights bf16 [32][2048] LDS-stationary, XOR-swizzled. 32x32x16 MFMA,
// 8 waves = 2 M-tiles(32) x 4 K-quarters(256). h double-buffered in ws with
// k-packed layout [k/8][b][8]; x pre-packed the same way; m pre-transposed.
// Grid barrier: release-add by tid0, relaxed per-wave spin + acquire fence.

#define B_ 64
#define T_ 512
#define D_ 1024
#define H_ 1024
#define NBLK 128
#define UPB 8
#define NROW 32
#define NTHR 512

typedef __attribute__((ext_vector_type(8))) short short8;
typedef __attribute__((ext_vector_type(16))) float f32x16;

// LDS layout (bytes):
//   [0,131072)  W: 32 rows x 2048 bf16, byte(r,k2) = (r*4096 + k2) ^ ((r&7)<<4)
//   gbuf: float[2][64][34], m_lds: float[64], bias_lds: float[32]
#define GBUF_OFF 131072
#define MLDS_OFF 148480
#define BIAS_OFF 148736
#define SMEM_BYTES 148864

// ws layout (bytes): bar@0 | mT@4096 (512*64 f32) | hbuf@135168 (2*128KB bf16,
// packed [kblk][b][8]) | xp@397312 (64MB bf16, packed [t][dblk][b][8])
#define WS_MT 4096
#define WS_HBUF 135168
#define WS_XP 397312
#define HBUF_HALF 65536  /* shorts per h buffer */

__device__ __forceinline__ unsigned f2bf(float f) {  // fp32 -> bf16 RNE
  unsigned u = __float_as_uint(f);
  return (u + 0x7FFFu + ((u >> 16) & 1u)) >> 16;
}
__device__ __forceinline__ float sigf(float x) { return 1.0f / (1.0f + __expf(-x)); }
__device__ __forceinline__ float tanhf_(float x) { return 1.0f - 2.0f / (__expf(2.0f * x) + 1.0f); }

__global__ void prep_m(const float* __restrict__ tm, float* __restrict__ mT) {
  int i = blockIdx.x * blockDim.x + threadIdx.x;  // over B*T
  if (i >= B_ * T_) return;
  int b = i >> 9, t = i & (T_ - 1);
  mT[t * B_ + b] = tm[i];
}

__global__ void prep_x(const float* __restrict__ x, unsigned short* __restrict__ xp) {
  int i = blockIdx.x * blockDim.x + threadIdx.x;  // over B*T*D/8 short8 groups
  if (i >= B_ * T_ * D_ / 8) return;
  int b = i & 63;
  int dblk = (i >> 6) & 127;
  int t = i >> 13;
  const float4* src = (const float4*)(x + ((size_t)b * T_ + t) * D_ + dblk * 8);
  float4 a0 = src[0], a1 = src[1];
  short8 r;
  r[0] = (short)f2bf(a0.x); r[1] = (short)f2bf(a0.y);
  r[2] = (short)f2bf(a0.z); r[3] = (short)f2bf(a0.w);
  r[4] = (short)f2bf(a1.x); r[5] = (short)f2bf(a1.y);
  r[6] = (short)f2bf(a1.z); r[7] = (short)f2bf(a1.w);
  ((short8*)xp)[i] = r;
}

template<int XB>
__global__ __launch_bounds__(NTHR, 1)
void lstm_persist(const float* __restrict__ xf,
                  const unsigned short* __restrict__ xp,
                  const float* __restrict__ mT,
                  const float* __restrict__ Wx, const float* __restrict__ bxp,
                  const float* __restrict__ Wh, const float* __restrict__ bhp,
                  float* __restrict__ out,
                  unsigned short* __restrict__ hbuf,
                  unsigned* __restrict__ bar)
{
  extern __shared__ char smem[];
  float* gbuf     = (float*)(smem + GBUF_OFF);   // [2][64][34]
  float* m_lds    = (float*)(smem + MLDS_OFF);
  float* bias_lds = (float*)(smem + BIAS_OFF);

  const int tid = threadIdx.x;
  const int bid = blockIdx.x;

  // ---- stage weights -> LDS (bf16, swizzled), once ----
  for (int r = 0; r < NROW; ++r) {
    const int grow = (r >> 3) * H_ + bid * UPB + (r & 7);  // gate g=r>>3, unit u=r&7
    const unsigned swz = (unsigned)((r & 7) << 4);
    float2 v = ((const float2*)(Wx + (size_t)grow * D_))[tid];
    unsigned pk = f2bf(v.x) | (f2bf(v.y) << 16);
    *(unsigned*)(smem + (((unsigned)(r * 4096 + tid * 4)) ^ swz)) = pk;
    v = ((const float2*)(Wh + (size_t)grow * H_))[tid];
    pk = f2bf(v.x) | (f2bf(v.y) << 16);
    *(unsigned*)(smem + (((unsigned)(r * 4096 + 2048 + tid * 4)) ^ swz)) = pk;
  }
  if (tid < NROW) {
    const int grow = (tid >> 3) * H_ + bid * UPB + (tid & 7);
    bias_lds[tid] = bxp[grow] + bhp[grow];
  }

  const int lane = tid & 63;
  const int wid  = tid >> 6;   // 0..7
  const int mt   = wid >> 2;   // M-tile (32 batch rows)
  const int kq   = wid & 3;    // K-quarter (256)
  const int l31  = lane & 31;
  const int kg   = lane >> 5;  // 0..1
  const int m0   = mt * 32;

  const int arow_off = (m0 + l31) * 8;                  // shorts
  const unsigned nswz = (unsigned)((l31 & 7) << 4);
  const unsigned wrow = (unsigned)(l31 * 4096);
  const unsigned kb   = (unsigned)(kq * 512 + kg * 16); // byte offset of k in row

  const int cb = tid >> 3;  // cell: batch
  const int cu = tid & 7;   // cell: unit
  float ccell = 0.0f, hv = 0.0f;

  unsigned cur = 0;
  __syncthreads();

  for (int t = 0; t < T_; ++t) {
    if (tid < B_) m_lds[tid] = mT[t * B_ + tid];

    // ---- issue all A-frag loads up front ----
    const unsigned short* hb = hbuf + cur * HBUF_HALF + (kq * 32 + kg) * 512 + arow_off;
    short8 ah[16], ax[16];
#pragma unroll
    for (int ks = 0; ks < 16; ++ks) ah[ks] = *(const short8*)(hb + ks * 1024);
    if (XB) {
      const unsigned short* xb2 = xp + ((size_t)t * 128 + kq * 32 + kg) * 512 + arow_off;
#pragma unroll
      for (int ks = 0; ks < 16; ++ks) ax[ks] = *(const short8*)(xb2 + ks * 1024);
    } else {
      const float* xsrc = xf + ((size_t)(m0 + l31) * T_ + t) * D_ + kq * 256 + kg * 8;
#pragma unroll
      for (int ks = 0; ks < 16; ++ks) {
        float4 a0 = *(const float4*)(xsrc + ks * 16);
        float4 a1 = *(const float4*)(xsrc + ks * 16 + 4);
        short8 r;
        r[0] = (short)f2bf(a0.x); r[1] = (short)f2bf(a0.y);
        r[2] = (short)f2bf(a0.z); r[3] = (short)f2bf(a0.w);
        r[4] = (short)f2bf(a1.x); r[5] = (short)f2bf(a1.y);
        r[6] = (short)f2bf(a1.z); r[7] = (short)f2bf(a1.w);
        ax[ks] = r;
      }
    }

    f32x16 accA = {0,0,0,0,0,0,0,0,0,0,0,0,0,0,0,0};  // h@Wx^T
    f32x16 accB = {0,0,0,0,0,0,0,0,0,0,0,0,0,0,0,0};  // x@Wx^T
    f32x16 accC = {0,0,0,0,0,0,0,0,0,0,0,0,0,0,0,0};  // h@Wh^T
#pragma unroll
    for (int ks = 0; ks < 16; ++ks) {
      const unsigned kk = kb + (unsigned)(ks * 32);
      short8 bwx = *(const short8*)(smem + ((wrow + kk) ^ nswz));
      short8 bwh = *(const short8*)(smem + ((wrow + 2048 + kk) ^ nswz));
      accA = __builtin_amdgcn_mfma_f32_32x32x16_bf16(ah[ks], bwx, accA, 0, 0, 0);
      accB = __builtin_amdgcn_mfma_f32_32x32x16_bf16(ax[ks], bwx, accB, 0, 0, 0);
      accC = __builtin_amdgcn_mfma_f32_32x32x16_bf16(ah[ks], bwh, accC, 0, 0, 0);
    }

    __syncthreads();  // (A) m_lds ready; prev cell reads long done
    // C layout (32x32): col = lane&31, row = (e&3) + 8*(e>>2) + 4*(lane>>5)
    const int s = kq >> 1;
    if ((kq & 1) == 0) {
#pragma unroll
      for (int e = 0; e < 16; ++e) {
        const int br = m0 + (e & 3) + 8 * (e >> 2) + 4 * kg;
        const float mv = m_lds[br];
        float g = mv * accA[e] + (1.0f - mv) * accB[e] + accC[e];
        if (kq == 0) g += bias_lds[l31];
        gbuf[(s * 64 + br) * 34 + l31] = g;
      }
    }
    __syncthreads();  // (B)
    if (kq & 1) {
#pragma unroll
      for (int e = 0; e < 16; ++e) {
        const int br = m0 + (e & 3) + 8 * (e >> 2) + 4 * kg;
        const float mv = m_lds[br];
        float g = mv * accA[e] + (1.0f - mv) * accB[e] + accC[e];
        gbuf[(s * 64 + br) * 34 + l31] += g;
      }
    }
    __syncthreads();  // (C)

    // ---- cell: one (b,u) per thread ----
    {
      const float* g0 = gbuf + cb * 34;
      const float* g1 = gbuf + (64 + cb) * 34;
      const float gi = g0[cu]      + g1[cu];
      const float gf = g0[8 + cu]  + g1[8 + cu];
      const float gg = g0[16 + cu] + g1[16 + cu];
      const float go = g0[24 + cu] + g1[24 + cu];
      const float iv = sigf(gi), fv = sigf(gf), gv = tanhf_(gg), ov = sigf(go);
      ccell = ccell * fv + iv * gv;
      hv = ov * tanhf_(ccell);
      out[((size_t)cb * T_ + t) * H_ + bid * UPB + cu] = hv;
      // packed h: block writes contiguous 512 shorts at bid*512
      hbuf[(cur ^ 1u) * HBUF_HALF + bid * 512 + tid] = (unsigned short)f2bf(hv);
    }

    __syncthreads();  // drains all stores (vmcnt 0) + gbuf consumed
    if (tid == 0)
      __hip_atomic_fetch_add(bar, 1u, __ATOMIC_RELEASE, __HIP_MEMORY_SCOPE_AGENT);
    const unsigned target = (unsigned)(t + 1) * NBLK;
    while (__hip_atomic_load(bar, __ATOMIC_RELAXED, __HIP_MEMORY_SCOPE_AGENT) < target)
      __builtin_amdgcn_s_sleep(2);
    __builtin_amdgcn_fence(__ATOMIC_ACQUIRE, "agent");
    cur ^= 1u;
  }

  // finals: hn, cn
  out[(size_t)B_ * T_ * H_ + (size_t)cb * H_ + bid * UPB + cu] = hv;
  out[(size_t)B_ * T_ * H_ + (size_t)B_ * H_ + (size_t)cb * H_ + bid * UPB + cu] = ccell;
}

extern "C" void kernel_launch(void* const* d_in, const int* in_sizes, int n_in,
                              void* d_out, int out_size, void* d_ws, size_t ws_size,
                              hipStream_t stream) {
  const float* x  = (const float*)d_in[0];
  const float* tm = (const float*)d_in[1];
  const float* Wx = (const float*)d_in[2];
  const float* bx = (const float*)d_in[3];
  const float* Wh = (const float*)d_in[4];
  const float* bh = (const float*)d_in[5];
  float* out = (float*)d_out;
  char* ws = (char*)d_ws;

  unsigned* bar        = (unsigned*)ws;
  float* mT            = (float*)(ws + WS_MT);
  unsigned short* hbuf = (unsigned short*)(ws + WS_HBUF);
  unsigned short* xp   = (unsigned short*)(ws + WS_XP);
  const size_t need_xp = (size_t)WS_XP + 2ull * B_ * T_ * D_;
  const bool use_xp = ws_size >= need_xp;

  hipMemsetAsync(ws, 0, WS_XP, stream);  // zero bar + mT + both h buffers
  {
    const int n = B_ * T_;
    prep_m<<<dim3((n + 255) / 256), dim3(256), 0, stream>>>(tm, mT);
  }
  if (use_xp) {
    const int n = B_ * T_ * D_ / 8;
    prep_x<<<dim3((n + 255) / 256), dim3(256), 0, stream>>>(x, xp);
    lstm_persist<1><<<dim3(NBLK), dim3(NTHR), SMEM_BYTES, stream>>>(
        x, xp, mT, Wx, bx, Wh, bh, out, hbuf, bar);
  } else {
    lstm_persist<0><<<dim3(NBLK), dim3(NTHR), SMEM_BYTES, stream>>>(
        x, xp, mT, Wx, bx, Wh, bh, out, hbuf, bar);
  }
}

// Round 3
// 9143.947 us; speedup vs baseline: 1.4204x; 1.4204x over previous
//
#include <hip/hip_runtime.h>
#include <stdint.h>

// Teacher-forced LSTM, B=64 T=512 D=H=1024.
// gates = m.(h@Wx^T) + (1-m).(x@Wx^T) + h@Wh^T + bx + bh
// Persistent: 128 blocks x 512 thr; block owns 8 hidden units (32 gate rows).
// Weights bf16 [32][2048] LDS-stationary, 16-slot XOR swizzle. 32x32x16 MFMA,
// 8 waves = 2 M-tiles(32) x 4 K-quarters(256). h double-buffered in ws
// ([kblk][b][8] packed); x pre-packed same; m pre-transposed.
// Grid barrier: per-block padded arrive flag (store-release), 128 read-only
// pollers/block, no atomics. x(t+1)/m(t+1) prefetched under epilogue+barrier.

#define B_ 64
#define T_ 512
#define D_ 1024
#define H_ 1024
#define NBLK 128
#define UPB 8
#define NROW 32
#define NTHR 512

typedef __attribute__((ext_vector_type(8))) short short8;
typedef __attribute__((ext_vector_type(16))) float f32x16;

// LDS layout (bytes):
//   [0,131072)  W: 32 rows x 2048 bf16, byte(r,k2) = (r*4096 + k2) ^ ((r&15)<<4)
//   gbuf: float[2][64][34] @131072, m_lds: float[2][64] @148480, bias @148992
#define GBUF_OFF 131072
#define MLDS_OFF 148480
#define BIAS_OFF 148992
#define SMEM_BYTES 149120

// ws layout (bytes): flags@0 (128*128B) | mT@16384 (512*64 f32) |
// hbuf@147456 (2*128KB bf16 packed [kblk][b][8]) | xp@409600 (64MB bf16)
#define WS_MT 16384
#define WS_HBUF 147456
#define WS_XP 409600
#define HBUF_HALF 65536 /* shorts per h buffer */

__device__ __forceinline__ unsigned f2bf(float f) {  // fp32 -> bf16 RNE
  unsigned u = __float_as_uint(f);
  return (u + 0x7FFFu + ((u >> 16) & 1u)) >> 16;
}
__device__ __forceinline__ float sigf(float x) { return 1.0f / (1.0f + __expf(-x)); }
__device__ __forceinline__ float tanhf_(float x) { return 1.0f - 2.0f / (__expf(2.0f * x) + 1.0f); }

__global__ void prep_m(const float* __restrict__ tm, float* __restrict__ mT) {
  int i = blockIdx.x * blockDim.x + threadIdx.x;  // over B*T
  if (i >= B_ * T_) return;
  int b = i >> 9, t = i & (T_ - 1);
  mT[t * B_ + b] = tm[i];
}

__global__ void prep_x(const float* __restrict__ x, unsigned short* __restrict__ xp) {
  int i = blockIdx.x * blockDim.x + threadIdx.x;  // over B*T*D/8 short8 groups
  if (i >= B_ * T_ * D_ / 8) return;
  int b = i & 63;
  int dblk = (i >> 6) & 127;
  int t = i >> 13;
  const float4* src = (const float4*)(x + ((size_t)b * T_ + t) * D_ + dblk * 8);
  float4 a0 = src[0], a1 = src[1];
  short8 r;
  r[0] = (short)f2bf(a0.x); r[1] = (short)f2bf(a0.y);
  r[2] = (short)f2bf(a0.z); r[3] = (short)f2bf(a0.w);
  r[4] = (short)f2bf(a1.x); r[5] = (short)f2bf(a1.y);
  r[6] = (short)f2bf(a1.z); r[7] = (short)f2bf(a1.w);
  ((short8*)xp)[i] = r;
}

template<int XB>
__global__ __launch_bounds__(NTHR, 1)
void lstm_persist(const float* __restrict__ xf,
                  const unsigned short* __restrict__ xp,
                  const float* __restrict__ mT,
                  const float* __restrict__ Wx, const float* __restrict__ bxp,
                  const float* __restrict__ Wh, const float* __restrict__ bhp,
                  float* __restrict__ out,
                  unsigned short* __restrict__ hbuf,
                  unsigned* __restrict__ flags)
{
  extern __shared__ char smem[];
  float* gbuf     = (float*)(smem + GBUF_OFF);  // [2][64][34]
  float* m_lds    = (float*)(smem + MLDS_OFF);  // [2][64]
  float* bias_lds = (float*)(smem + BIAS_OFF);

  const int tid = threadIdx.x;
  const int bid = blockIdx.x;

  // ---- stage weights -> LDS (bf16, 16-slot swizzle), once ----
  for (int r = 0; r < NROW; ++r) {
    const int grow = (r >> 3) * H_ + bid * UPB + (r & 7);  // gate g=r>>3, unit u=r&7
    const unsigned swz = (unsigned)((r & 15) << 4);
    float2 v = ((const float2*)(Wx + (size_t)grow * D_))[tid];
    *(unsigned*)(smem + (((unsigned)(r * 4096 + tid * 4)) ^ swz)) =
        f2bf(v.x) | (f2bf(v.y) << 16);
    v = ((const float2*)(Wh + (size_t)grow * H_))[tid];
    *(unsigned*)(smem + (((unsigned)(r * 4096 + 2048 + tid * 4)) ^ swz)) =
        f2bf(v.x) | (f2bf(v.y) << 16);
  }
  if (tid < NROW) {
    const int grow = (tid >> 3) * H_ + bid * UPB + (tid & 7);
    bias_lds[tid] = bxp[grow] + bhp[grow];
  }

  const int lane = tid & 63;
  const int wid  = tid >> 6;   // 0..7
  const int mt   = wid >> 2;   // M-tile (32 batch rows)
  const int kq   = wid & 3;    // K-quarter (256)
  const int l31  = lane & 31;
  const int kg   = lane >> 5;  // 0..1
  const int m0   = mt * 32;

  const int arow_off  = (m0 + l31) * 8;                   // shorts
  const unsigned nswz = (unsigned)((l31 & 15) << 4);
  const unsigned wrow = (unsigned)(l31 * 4096);
  const unsigned kb   = (unsigned)(kq * 512 + kg * 16);   // k byte offset in row

  const int cb = tid >> 3;  // cell: batch
  const int cu = tid & 7;   // cell: unit
  float ccell = 0.0f, hv = 0.0f;

  // ---- preload m(0) and x(0) ----
  if (tid < B_) m_lds[tid] = mT[tid];
  short8 ax[16];
  if (XB) {
    const unsigned short* xb2 = xp + ((size_t)(kq * 32 + kg)) * 512 + arow_off;
#pragma unroll
    for (int ks = 0; ks < 16; ++ks) ax[ks] = *(const short8*)(xb2 + ks * 1024);
  } else {
    const float* xsrc = xf + ((size_t)(m0 + l31) * T_) * D_ + kq * 256 + kg * 8;
#pragma unroll
    for (int ks = 0; ks < 16; ++ks) {
      float4 a0 = *(const float4*)(xsrc + ks * 16);
      float4 a1 = *(const float4*)(xsrc + ks * 16 + 4);
      short8 r;
      r[0] = (short)f2bf(a0.x); r[1] = (short)f2bf(a0.y);
      r[2] = (short)f2bf(a0.z); r[3] = (short)f2bf(a0.w);
      r[4] = (short)f2bf(a1.x); r[5] = (short)f2bf(a1.y);
      r[6] = (short)f2bf(a1.z); r[7] = (short)f2bf(a1.w);
      ax[ks] = r;
    }
  }
  unsigned cur = 0;
  __syncthreads();

  for (int t = 0; t < T_; ++t) {
    const int nxt = (t + 1 < T_) ? (t + 1) : t;  // clamped prefetch index

    // issue m(t+1) prefetch early (wave 0 only; non-divergent)
    float mnext = 0.0f;
    if (tid < B_) mnext = mT[nxt * B_ + tid];

    // ---- h A-frag loads (critical path after barrier) ----
    const unsigned short* hb = hbuf + cur * HBUF_HALF + (kq * 32 + kg) * 512 + arow_off;
    short8 ah[16];
#pragma unroll
    for (int ks = 0; ks < 16; ++ks) ah[ks] = *(const short8*)(hb + ks * 1024);

    f32x16 accA = {0,0,0,0,0,0,0,0,0,0,0,0,0,0,0,0};  // h@Wx^T
    f32x16 accB = {0,0,0,0,0,0,0,0,0,0,0,0,0,0,0,0};  // x@Wx^T
    f32x16 accC = {0,0,0,0,0,0,0,0,0,0,0,0,0,0,0,0};  // h@Wh^T
#pragma unroll
    for (int ks = 0; ks < 16; ++ks) {
      const unsigned kk = kb + (unsigned)(ks * 32);
      short8 bwx = *(const short8*)(smem + ((wrow + kk) ^ nswz));
      short8 bwh = *(const short8*)(smem + ((wrow + 2048 + kk) ^ nswz));
      accA = __builtin_amdgcn_mfma_f32_32x32x16_bf16(ah[ks], bwx, accA, 0, 0, 0);
      accB = __builtin_amdgcn_mfma_f32_32x32x16_bf16(ax[ks], bwx, accB, 0, 0, 0);
      accC = __builtin_amdgcn_mfma_f32_32x32x16_bf16(ah[ks], bwh, accC, 0, 0, 0);
    }

    // ---- prefetch x(t+1) into regs (hidden under epilogue+cell+barrier) ----
    short8 axn[16];
    if (XB) {
      const unsigned short* xb2 = xp + ((size_t)nxt * 128 + kq * 32 + kg) * 512 + arow_off;
#pragma unroll
      for (int ks = 0; ks < 16; ++ks) axn[ks] = *(const short8*)(xb2 + ks * 1024);
    } else {
      const float* xsrc = xf + ((size_t)(m0 + l31) * T_ + nxt) * D_ + kq * 256 + kg * 8;
#pragma unroll
      for (int ks = 0; ks < 16; ++ks) {
        float4 a0 = *(const float4*)(xsrc + ks * 16);
        float4 a1 = *(const float4*)(xsrc + ks * 16 + 4);
        short8 r;
        r[0] = (short)f2bf(a0.x); r[1] = (short)f2bf(a0.y);
        r[2] = (short)f2bf(a0.z); r[3] = (short)f2bf(a0.w);
        r[4] = (short)f2bf(a1.x); r[5] = (short)f2bf(a1.y);
        r[6] = (short)f2bf(a1.z); r[7] = (short)f2bf(a1.w);
        axn[ks] = r;
      }
    }
    if (tid < B_) m_lds[((t + 1) & 1) * B_ + tid] = mnext;

    __syncthreads();  // (A) m_lds[t&1] + gbuf WAR safe
    const float* ml = m_lds + (t & 1) * B_;
    const int s = kq >> 1;
    // C layout (32x32): col = lane&31, row = (e&3) + 8*(e>>2) + 4*(lane>>5)
    if ((kq & 1) == 0) {
#pragma unroll
      for (int e = 0; e < 16; ++e) {
        const int br = m0 + (e & 3) + 8 * (e >> 2) + 4 * kg;
        const float mv = ml[br];
        float g = mv * accA[e] + (1.0f - mv) * accB[e] + accC[e];
        if (kq == 0) g += bias_lds[l31];
        gbuf[(s * 64 + br) * 34 + l31] = g;
      }
    }
    __syncthreads();  // (B)
    if (kq & 1) {
#pragma unroll
      for (int e = 0; e < 16; ++e) {
        const int br = m0 + (e & 3) + 8 * (e >> 2) + 4 * kg;
        const float mv = ml[br];
        float g = mv * accA[e] + (1.0f - mv) * accB[e] + accC[e];
        gbuf[(s * 64 + br) * 34 + l31] += g;
      }
    }
    __syncthreads();  // (C)

    // ---- cell: one (b,u) per thread ----
    {
      const float* g0 = gbuf + cb * 34;
      const float* g1 = gbuf + (64 + cb) * 34;
      const float gi = g0[cu]      + g1[cu];
      const float gf = g0[8 + cu]  + g1[8 + cu];
      const float gg = g0[16 + cu] + g1[16 + cu];
      const float go = g0[24 + cu] + g1[24 + cu];
      const float iv = sigf(gi), fv = sigf(gf), gv = tanhf_(gg), ov = sigf(go);
      ccell = ccell * fv + iv * gv;
      hv = ov * tanhf_(ccell);
      out[((size_t)cb * T_ + t) * H_ + bid * UPB + cu] = hv;
      hbuf[(cur ^ 1u) * HBUF_HALF + bid * 512 + tid] = (unsigned short)f2bf(hv);
    }

    __syncthreads();  // (D) drains all stores (implicit vmcnt(0) before s_barrier)
    if (tid == 0) {
      __builtin_amdgcn_fence(__ATOMIC_RELEASE, "agent");
      __hip_atomic_store(flags + bid * 32, (unsigned)(t + 1),
                         __ATOMIC_RELAXED, __HIP_MEMORY_SCOPE_AGENT);
    }
    if (tid < NBLK) {
      const unsigned* f = flags + tid * 32;  // each thread its own read-only line
      while (__hip_atomic_load(f, __ATOMIC_RELAXED, __HIP_MEMORY_SCOPE_AGENT) <
             (unsigned)(t + 1))
        __builtin_amdgcn_s_sleep(2);
    }
    __syncthreads();  // (E)
    __builtin_amdgcn_fence(__ATOMIC_ACQUIRE, "agent");

    cur ^= 1u;
#pragma unroll
    for (int ks = 0; ks < 16; ++ks) ax[ks] = axn[ks];
  }

  // finals: hn, cn
  out[(size_t)B_ * T_ * H_ + (size_t)cb * H_ + bid * UPB + cu] = hv;
  out[(size_t)B_ * T_ * H_ + (size_t)B_ * H_ + (size_t)cb * H_ + bid * UPB + cu] = ccell;
}

extern "C" void kernel_launch(void* const* d_in, const int* in_sizes, int n_in,
                              void* d_out, int out_size, void* d_ws, size_t ws_size,
                              hipStream_t stream) {
  const float* x  = (const float*)d_in[0];
  const float* tm = (const float*)d_in[1];
  const float* Wx = (const float*)d_in[2];
  const float* bx = (const float*)d_in[3];
  const float* Wh = (const float*)d_in[4];
  const float* bh = (const float*)d_in[5];
  float* out = (float*)d_out;
  char* ws = (char*)d_ws;

  unsigned* flags      = (unsigned*)ws;
  float* mT            = (float*)(ws + WS_MT);
  unsigned short* hbuf = (unsigned short*)(ws + WS_HBUF);
  unsigned short* xp   = (unsigned short*)(ws + WS_XP);
  const size_t need_xp = (size_t)WS_XP + 2ull * B_ * T_ * D_;
  const bool use_xp = ws_size >= need_xp;

  hipMemsetAsync(ws, 0, WS_XP, stream);  // zero flags + mT + both h buffers
  {
    const int n = B_ * T_;
    prep_m<<<dim3((n + 255) / 256), dim3(256), 0, stream>>>(tm, mT);
  }
  if (use_xp) {
    const int n = B_ * T_ * D_ / 8;
    prep_x<<<dim3((n + 255) / 256), dim3(256), 0, stream>>>(x, xp);
    lstm_persist<1><<<dim3(NBLK), dim3(NTHR), SMEM_BYTES, stream>>>(
        x, xp, mT, Wx, bx, Wh, bh, out, hbuf, flags);
  } else {
    lstm_persist<0><<<dim3(NBLK), dim3(NTHR), SMEM_BYTES, stream>>>(
        x, xp, mT, Wx, bx, Wh, bh, out, hbuf, flags);
  }
}

// Round 4
// 5381.338 us; speedup vs baseline: 2.4135x; 1.6992x over previous
//
#include <hip/hip_runtime.h>
#include <stdint.h>

// Teacher-forced LSTM, B=64 T=512 D=H=1024.
// a(t) = m(t)*h(t-1) + (1-m(t))*x(t)  (computed in previous step's cell phase)
// gates(t) = [a(t) | h(t-1)] @ [Wx | Wh]^T + bias   -- one K=2048 GEMM
// Persistent: 128 blocks x 512 thr; block owns 8 hidden units (32 gate rows).
// Weights bf16 [32 rows][4096B = Wx row | Wh row] LDS-stationary, 16-slot XOR
// swizzle. 32x32x16 MFMA; 8 waves = 2 M-tiles(32) x 4 K-quarters(512).
// [a|h] double-buffered coherent buffer in ws ([kblk][b][8] bf16), accessed
// with __hip_atomic (agent scope) -- NO cache-wide fences anywhere.
// Grid barrier: packed 4B flags, store by tid0, wave-0 polls all 128.

#define B_ 64
#define T_ 512
#define D_ 1024
#define H_ 1024
#define NBLK 128
#define UPB 8
#define NROW 32
#define NTHR 512

typedef __attribute__((ext_vector_type(8))) short short8;
typedef __attribute__((ext_vector_type(16))) float f32x16;

// LDS (bytes): W 32x4096 swizzled @0 | gbuf float[2][64][33] @131072 | bias @147968
#define GBUF_OFF 131072
#define BIAS_OFF 147968
#define SMEM_BYTES 148096

// ws (bytes): flags[128] u32 @0 (4KB region) | abuf @4096: [2][256][64][8] bf16
#define WS_ABUF 4096
#define ABUF_HALF (256 * 64 * 8) /* shorts per buffer */

__device__ __forceinline__ unsigned f2bf(float f) {  // fp32 -> bf16 RNE
  unsigned u = __float_as_uint(f);
  return (u + 0x7FFFu + ((u >> 16) & 1u)) >> 16;
}
__device__ __forceinline__ float sigf(float x) { return 1.0f / (1.0f + __expf(-x)); }
__device__ __forceinline__ float tanhf_(float x) { return 1.0f - 2.0f / (__expf(2.0f * x) + 1.0f); }

// a(0) = (1-m(0))*x(0); h(0)=0 already zeroed by memset.
__global__ void prep_a0(const float* __restrict__ x, const float* __restrict__ tm,
                        unsigned short* __restrict__ abuf) {
  int i = blockIdx.x * blockDim.x + threadIdx.x;  // over B_*D_
  if (i >= B_ * D_) return;
  int unit = i & (D_ - 1), b = i >> 10;
  float m = tm[b * T_];
  float a = (1.0f - m) * x[(size_t)b * T_ * D_ + unit];
  abuf[((unit >> 3) * 64 + b) * 8 + (unit & 7)] = (unsigned short)f2bf(a);
}

__global__ __launch_bounds__(NTHR, 1)
void lstm_persist(const float* __restrict__ xf,
                  const float* __restrict__ tm,
                  const float* __restrict__ Wx, const float* __restrict__ bxp,
                  const float* __restrict__ Wh, const float* __restrict__ bhp,
                  float* __restrict__ out,
                  unsigned short* __restrict__ abuf,
                  unsigned* __restrict__ flags)
{
  extern __shared__ char smem[];
  float* gbuf     = (float*)(smem + GBUF_OFF);  // [2][64][33]
  float* bias_lds = (float*)(smem + BIAS_OFF);

  const int tid = threadIdx.x;
  const int bid = blockIdx.x;

  // ---- stage weights -> LDS: row r = [Wx grow | Wh grow], 4096B, swizzled ----
  for (int r = 0; r < NROW; ++r) {
    const int grow = (r >> 3) * H_ + bid * UPB + (r & 7);  // gate g=r>>3, unit u=r&7
    const unsigned swz = (unsigned)((r & 15) << 4);
    float2 v = ((const float2*)(Wx + (size_t)grow * D_))[tid];
    *(unsigned*)(smem + (((unsigned)(r * 4096 + tid * 4)) ^ swz)) =
        f2bf(v.x) | (f2bf(v.y) << 16);
    v = ((const float2*)(Wh + (size_t)grow * H_))[tid];
    *(unsigned*)(smem + (((unsigned)(r * 4096 + 2048 + tid * 4)) ^ swz)) =
        f2bf(v.x) | (f2bf(v.y) << 16);
  }
  if (tid < NROW) {
    const int grow = (tid >> 3) * H_ + bid * UPB + (tid & 7);
    bias_lds[tid] = bxp[grow] + bhp[grow];
  }

  const int lane = tid & 63;
  const int wid  = tid >> 6;   // 0..7
  const int mt   = wid >> 2;   // M-tile (32 batch rows)
  const int kq   = wid & 3;    // K-quarter of 2048 (512 each)
  const int l31  = lane & 31;
  const int kg   = lane >> 5;  // 0..1
  const int m0   = mt * 32;

  const unsigned nswz = (unsigned)((l31 & 15) << 4);
  const unsigned wrow = (unsigned)(l31 * 4096);
  const unsigned kbase = (unsigned)(kq * 1024 + kg * 16);  // byte offset in 4096B row

  const int cb = tid >> 3;  // cell: batch
  const int cu = tid & 7;   // cell: unit within block
  float ccell = 0.0f, hv = 0.0f;

  unsigned cur = 0;
  __syncthreads();

  for (int t = 0; t < T_; ++t) {
    const int nxt = (t + 1 < T_) ? (t + 1) : t;

    // cell-phase operands for this step (plain cached; latency-hidden)
    const float mv = tm[cb * T_ + nxt];
    const float xv = xf[((size_t)cb * T_ + nxt) * D_ + bid * UPB + cu];

    // ---- A-frags: 32 x 16B from coherent abuf (64 x 8B agent-scope loads) ----
    const unsigned long long* ap =
        (const unsigned long long*)(abuf + cur * ABUF_HALF) +
        ((size_t)((kq * 64 + kg) * 64 + (m0 + l31))) * 2;
    unsigned long long alo[32], ahi[32];
#pragma unroll
    for (int j = 0; j < 32; ++j) {
      alo[j] = __hip_atomic_load(ap + (size_t)j * 256,
                                 __ATOMIC_RELAXED, __HIP_MEMORY_SCOPE_AGENT);
      ahi[j] = __hip_atomic_load(ap + (size_t)j * 256 + 1,
                                 __ATOMIC_RELAXED, __HIP_MEMORY_SCOPE_AGENT);
    }

    f32x16 acc = {0,0,0,0,0,0,0,0,0,0,0,0,0,0,0,0};
#pragma unroll
    for (int j = 0; j < 32; ++j) {
      short8 a;
      ((unsigned long long*)&a)[0] = alo[j];
      ((unsigned long long*)&a)[1] = ahi[j];
      short8 w = *(const short8*)(smem +
                  ((wrow + kbase + (unsigned)(j * 32)) ^ nswz));
      acc = __builtin_amdgcn_mfma_f32_32x32x16_bf16(a, w, acc, 0, 0, 0);
    }

    // ---- cross-kq reduce: kq even writes slab, kq odd adds ----
    // C layout (32x32): col = lane&31, row = (e&3) + 8*(e>>2) + 4*(lane>>5)
    const int s = kq >> 1;
    if ((kq & 1) == 0) {
#pragma unroll
      for (int e = 0; e < 16; ++e) {
        const int br = m0 + (e & 3) + 8 * (e >> 2) + 4 * kg;
        float g = acc[e];
        if (kq == 0) g += bias_lds[l31];
        gbuf[(s * 64 + br) * 33 + l31] = g;
      }
    }
    __syncthreads();  // (B)
    if (kq & 1) {
#pragma unroll
      for (int e = 0; e < 16; ++e) {
        const int br = m0 + (e & 3) + 8 * (e >> 2) + 4 * kg;
        gbuf[(s * 64 + br) * 33 + l31] += acc[e];
      }
    }
    __syncthreads();  // (C)

    // ---- cell: one (b,u) per thread ----
    {
      const float* g0 = gbuf + cb * 33;
      const float* g1 = gbuf + (64 + cb) * 33;
      const float gi = g0[cu]      + g1[cu];
      const float gf = g0[8 + cu]  + g1[8 + cu];
      const float gg = g0[16 + cu] + g1[16 + cu];
      const float go = g0[24 + cu] + g1[24 + cu];
      const float iv = sigf(gi), fv = sigf(gf), gv = tanhf_(gg), ov = sigf(go);
      ccell = ccell * fv + iv * gv;
      hv = ov * tanhf_(ccell);
      out[((size_t)cb * T_ + t) * H_ + bid * UPB + cu] = hv;

      const float av = mv * hv + (1.0f - mv) * xv;  // a(t+1) for this unit
      unsigned short* dst = abuf + (cur ^ 1u) * ABUF_HALF;
      __hip_atomic_store(dst + (bid * 64 + cb) * 8 + cu,
                         (unsigned short)f2bf(av),
                         __ATOMIC_RELAXED, __HIP_MEMORY_SCOPE_AGENT);
      __hip_atomic_store(dst + ((128 + bid) * 64 + cb) * 8 + cu,
                         (unsigned short)f2bf(hv),
                         __ATOMIC_RELAXED, __HIP_MEMORY_SCOPE_AGENT);
    }

    __syncthreads();  // (D) drains all stores (vmcnt(0) before s_barrier)
    if (tid == 0)
      __hip_atomic_store(&flags[bid], (unsigned)(t + 1),
                         __ATOMIC_RELAXED, __HIP_MEMORY_SCOPE_AGENT);
    if (wid == 0) {  // wave 0 polls all 128 packed flags
      const unsigned tgt = (unsigned)(t + 1);
      while (true) {
        unsigned f0 = __hip_atomic_load(&flags[lane],
                                        __ATOMIC_RELAXED, __HIP_MEMORY_SCOPE_AGENT);
        unsigned f1 = __hip_atomic_load(&flags[64 + lane],
                                        __ATOMIC_RELAXED, __HIP_MEMORY_SCOPE_AGENT);
        if (__all((f0 >= tgt) && (f1 >= tgt))) break;
        __builtin_amdgcn_s_sleep(1);
      }
    }
    __syncthreads();  // (E)
    __builtin_amdgcn_fence(__ATOMIC_ACQUIRE, "workgroup");  // compiler/wave order only

    cur ^= 1u;
  }

  // finals: hn, cn
  out[(size_t)B_ * T_ * H_ + (size_t)cb * H_ + bid * UPB + cu] = hv;
  out[(size_t)B_ * T_ * H_ + (size_t)B_ * H_ + (size_t)cb * H_ + bid * UPB + cu] = ccell;
}

extern "C" void kernel_launch(void* const* d_in, const int* in_sizes, int n_in,
                              void* d_out, int out_size, void* d_ws, size_t ws_size,
                              hipStream_t stream) {
  const float* x  = (const float*)d_in[0];
  const float* tm = (const float*)d_in[1];
  const float* Wx = (const float*)d_in[2];
  const float* bx = (const float*)d_in[3];
  const float* Wh = (const float*)d_in[4];
  const float* bh = (const float*)d_in[5];
  float* out = (float*)d_out;
  char* ws = (char*)d_ws;

  unsigned* flags      = (unsigned*)ws;
  unsigned short* abuf = (unsigned short*)(ws + WS_ABUF);

  // zero flags + both [a|h] buffers (h(0)=0 comes from this)
  hipMemsetAsync(ws, 0, WS_ABUF + 2 * ABUF_HALF * 2, stream);
  prep_a0<<<dim3((B_ * D_ + 255) / 256), dim3(256), 0, stream>>>(x, tm, abuf);
  lstm_persist<<<dim3(NBLK), dim3(NTHR), SMEM_BYTES, stream>>>(
      x, tm, Wx, bx, Wh, bh, out, abuf, flags);
}

// Round 5
// 4169.312 us; speedup vs baseline: 3.1151x; 1.2907x over previous
//
#include <hip/hip_runtime.h>
#include <stdint.h>

// Teacher-forced LSTM, B=64 T=512 D=H=1024.
// a(t) = m(t)*h(t-1) + (1-m(t))*x(t)  (computed in previous step's cell phase)
// gates(t) = [a(t) | h(t-1)] @ [Wx | Wh]^T + bias   -- one K=2048 GEMM
// Persistent: 128 blocks x 512 thr; block owns 8 hidden units (32 gate rows).
// Weights bf16 [32 rows][4096B = Wx row | Wh row] LDS-stationary, 16-slot XOR
// swizzle. 32x32x16 MFMA; 8 waves = 2 M-tiles(32) x 4 K-quarters(512).
// [a|h] double-buffered coherent buffer in ws, agent-scope atomics (no fences).
// Grid barrier: per-block flag -> master (block 0 wave 0) polls -> single gen
// word -> everyone polls one coalesced line. A-loads batched via sched_barrier.

#define B_ 64
#define T_ 512
#define D_ 1024
#define H_ 1024
#define NBLK 128
#define UPB 8
#define NROW 32
#define NTHR 512

typedef __attribute__((ext_vector_type(8))) short short8;
typedef __attribute__((ext_vector_type(16))) float f32x16;

// LDS (bytes): W 32x4096 swizzled @0 | gbuf float[2][64][33] @131072 | bias @147968
#define GBUF_OFF 131072
#define BIAS_OFF 147968
#define SMEM_BYTES 148096

// ws (bytes): flags[128] u32 @0 | gen u32 @2048 | abuf @4096: [2][256][64][8] bf16
#define WS_ABUF 4096
#define ABUF_HALF (256 * 64 * 8) /* shorts per buffer */

__device__ __forceinline__ unsigned f2bf(float f) {  // fp32 -> bf16 RNE
  unsigned u = __float_as_uint(f);
  return (u + 0x7FFFu + ((u >> 16) & 1u)) >> 16;
}
__device__ __forceinline__ float sigf(float x) { return 1.0f / (1.0f + __expf(-x)); }
__device__ __forceinline__ float tanhf_(float x) { return 1.0f - 2.0f / (__expf(2.0f * x) + 1.0f); }

// a(0) = (1-m(0))*x(0); h(0)=0 from memset.
__global__ void prep_a0(const float* __restrict__ x, const float* __restrict__ tm,
                        unsigned short* __restrict__ abuf) {
  int i = blockIdx.x * blockDim.x + threadIdx.x;  // over B_*D_
  if (i >= B_ * D_) return;
  int unit = i & (D_ - 1), b = i >> 10;
  float m = tm[b * T_];
  float a = (1.0f - m) * x[(size_t)b * T_ * D_ + unit];
  abuf[((unit >> 3) * 64 + b) * 8 + (unit & 7)] = (unsigned short)f2bf(a);
}

__global__ __launch_bounds__(NTHR, 1)
void lstm_persist(const float* __restrict__ xf,
                  const float* __restrict__ tm,
                  const float* __restrict__ Wx, const float* __restrict__ bxp,
                  const float* __restrict__ Wh, const float* __restrict__ bhp,
                  float* __restrict__ out,
                  unsigned short* __restrict__ abuf,
                  unsigned* __restrict__ flags,
                  unsigned* __restrict__ gen)
{
  extern __shared__ char smem[];
  float* gbuf     = (float*)(smem + GBUF_OFF);  // [2][64][33]
  float* bias_lds = (float*)(smem + BIAS_OFF);

  const int tid = threadIdx.x;
  const int bid = blockIdx.x;

  // ---- stage weights -> LDS: row r = [Wx grow | Wh grow], 4096B, swizzled ----
  for (int r = 0; r < NROW; ++r) {
    const int grow = (r >> 3) * H_ + bid * UPB + (r & 7);  // gate g=r>>3, unit u=r&7
    const unsigned swz = (unsigned)((r & 15) << 4);
    float2 v = ((const float2*)(Wx + (size_t)grow * D_))[tid];
    *(unsigned*)(smem + (((unsigned)(r * 4096 + tid * 4)) ^ swz)) =
        f2bf(v.x) | (f2bf(v.y) << 16);
    v = ((const float2*)(Wh + (size_t)grow * H_))[tid];
    *(unsigned*)(smem + (((unsigned)(r * 4096 + 2048 + tid * 4)) ^ swz)) =
        f2bf(v.x) | (f2bf(v.y) << 16);
  }
  if (tid < NROW) {
    const int grow = (tid >> 3) * H_ + bid * UPB + (tid & 7);
    bias_lds[tid] = bxp[grow] + bhp[grow];
  }

  const int lane = tid & 63;
  const int wid  = tid >> 6;   // 0..7
  const int mt   = wid >> 2;   // M-tile (32 batch rows)
  const int kq   = wid & 3;    // K-quarter of 2048 (512 each)
  const int l31  = lane & 31;
  const int kg   = lane >> 5;  // 0..1
  const int m0   = mt * 32;

  const unsigned nswz = (unsigned)((l31 & 15) << 4);
  const unsigned wrow = (unsigned)(l31 * 4096);
  const unsigned kbase = (unsigned)(kq * 1024 + kg * 16);  // byte offset in 4096B row

  const int cb = tid >> 3;  // cell: batch
  const int cu = tid & 7;   // cell: unit within block
  float ccell = 0.0f, hv = 0.0f;

  unsigned cur = 0;
  __syncthreads();

  for (int t = 0; t < T_; ++t) {
    const int nxt = (t + 1 < T_) ? (t + 1) : t;
    const unsigned tgt = (unsigned)(t + 1);

    // cell-phase operands for this step (plain cached; latency-hidden)
    const float mv = tm[cb * T_ + nxt];
    const float xv = xf[((size_t)cb * T_ + nxt) * D_ + bid * UPB + cu];

    // ---- A-frags: batch-issue all 64 agent-scope 8B loads, wait once ----
    const unsigned long long* ap =
        (const unsigned long long*)(abuf + cur * ABUF_HALF) +
        ((size_t)((kq * 64 + kg) * 64 + (m0 + l31))) * 2;
    unsigned long long av0[32], av1[32];
#pragma unroll
    for (int j = 0; j < 32; ++j) {
      av0[j] = __hip_atomic_load(ap + (size_t)j * 256,
                                 __ATOMIC_RELAXED, __HIP_MEMORY_SCOPE_AGENT);
      av1[j] = __hip_atomic_load(ap + (size_t)j * 256 + 1,
                                 __ATOMIC_RELAXED, __HIP_MEMORY_SCOPE_AGENT);
    }
    __builtin_amdgcn_sched_barrier(0);  // pin: all loads issued before MFMA chain

    f32x16 acc = {0,0,0,0,0,0,0,0,0,0,0,0,0,0,0,0};
#pragma unroll
    for (int j = 0; j < 32; ++j) {
      short8 a;
      ((unsigned long long*)&a)[0] = av0[j];
      ((unsigned long long*)&a)[1] = av1[j];
      short8 w = *(const short8*)(smem +
                  ((wrow + kbase + (unsigned)(j * 32)) ^ nswz));
      acc = __builtin_amdgcn_mfma_f32_32x32x16_bf16(a, w, acc, 0, 0, 0);
    }

    // ---- cross-kq reduce: kq even writes slab, kq odd adds ----
    // C layout (32x32): col = lane&31, row = (e&3) + 8*(e>>2) + 4*(lane>>5)
    const int s = kq >> 1;
    if ((kq & 1) == 0) {
#pragma unroll
      for (int e = 0; e < 16; ++e) {
        const int br = m0 + (e & 3) + 8 * (e >> 2) + 4 * kg;
        float g = acc[e];
        if (kq == 0) g += bias_lds[l31];
        gbuf[(s * 64 + br) * 33 + l31] = g;
      }
    }
    __syncthreads();  // (B)
    if (kq & 1) {
#pragma unroll
      for (int e = 0; e < 16; ++e) {
        const int br = m0 + (e & 3) + 8 * (e >> 2) + 4 * kg;
        gbuf[(s * 64 + br) * 33 + l31] += acc[e];
      }
    }
    __syncthreads();  // (C)

    // ---- cell: one (b,u) per thread; a/h stores only (out deferred) ----
    {
      const float* g0 = gbuf + cb * 33;
      const float* g1 = gbuf + (64 + cb) * 33;
      const float gi = g0[cu]      + g1[cu];
      const float gf = g0[8 + cu]  + g1[8 + cu];
      const float gg = g0[16 + cu] + g1[16 + cu];
      const float go = g0[24 + cu] + g1[24 + cu];
      const float iv = sigf(gi), fv = sigf(gf), gv = tanhf_(gg), ov = sigf(go);
      ccell = ccell * fv + iv * gv;
      hv = ov * tanhf_(ccell);

      const float av = mv * hv + (1.0f - mv) * xv;  // a(t+1) for this unit
      unsigned short* dst = abuf + (cur ^ 1u) * ABUF_HALF;
      __hip_atomic_store(dst + (bid * 64 + cb) * 8 + cu,
                         (unsigned short)f2bf(av),
                         __ATOMIC_RELAXED, __HIP_MEMORY_SCOPE_AGENT);
      __hip_atomic_store(dst + ((128 + bid) * 64 + cb) * 8 + cu,
                         (unsigned short)f2bf(hv),
                         __ATOMIC_RELAXED, __HIP_MEMORY_SCOPE_AGENT);
    }

    __syncthreads();  // (D) drains a/h stores (vmcnt(0) before s_barrier)

    if (bid == 0) {
      // master: poll all flags, then publish gen
      if (wid == 0) {
        const int i0 = 1 + lane;          // 1..64
        const int i1 = 65 + lane;         // 65..128 (>=128 skipped)
        for (;;) {
          unsigned v0 = __hip_atomic_load(flags + i0,
                                          __ATOMIC_RELAXED, __HIP_MEMORY_SCOPE_AGENT);
          unsigned v1 = (i1 < NBLK)
                          ? __hip_atomic_load(flags + i1,
                                              __ATOMIC_RELAXED, __HIP_MEMORY_SCOPE_AGENT)
                          : tgt;
          if (__all((v0 >= tgt) && (v1 >= tgt))) break;
          __builtin_amdgcn_s_sleep(1);
        }
        if (lane == 0)
          __hip_atomic_store(gen, tgt, __ATOMIC_RELAXED, __HIP_MEMORY_SCOPE_AGENT);
      }
      out[((size_t)cb * T_ + t) * H_ + bid * UPB + cu] = hv;  // off critical path
    } else {
      if (tid == 0)
        __hip_atomic_store(flags + bid, tgt,
                           __ATOMIC_RELAXED, __HIP_MEMORY_SCOPE_AGENT);
      out[((size_t)cb * T_ + t) * H_ + bid * UPB + cu] = hv;  // overlaps gen wait
      if (wid == 0) {
        while (__hip_atomic_load(gen, __ATOMIC_RELAXED, __HIP_MEMORY_SCOPE_AGENT) < tgt)
          __builtin_amdgcn_s_sleep(1);
      }
    }
    __syncthreads();  // (E)
    __builtin_amdgcn_sched_barrier(0);  // no A-load hoisting above the wait

    cur ^= 1u;
  }

  // finals: hn, cn
  out[(size_t)B_ * T_ * H_ + (size_t)cb * H_ + bid * UPB + cu] = hv;
  out[(size_t)B_ * T_ * H_ + (size_t)B_ * H_ + (size_t)cb * H_ + bid * UPB + cu] = ccell;
}

extern "C" void kernel_launch(void* const* d_in, const int* in_sizes, int n_in,
                              void* d_out, int out_size, void* d_ws, size_t ws_size,
                              hipStream_t stream) {
  const float* x  = (const float*)d_in[0];
  const float* tm = (const float*)d_in[1];
  const float* Wx = (const float*)d_in[2];
  const float* bx = (const float*)d_in[3];
  const float* Wh = (const float*)d_in[4];
  const float* bh = (const float*)d_in[5];
  float* out = (float*)d_out;
  char* ws = (char*)d_ws;

  unsigned* flags      = (unsigned*)ws;
  unsigned* gen        = (unsigned*)(ws + 2048);
  unsigned short* abuf = (unsigned short*)(ws + WS_ABUF);

  // zero flags + gen + both [a|h] buffers (h(0)=0 comes from this)
  hipMemsetAsync(ws, 0, WS_ABUF + 2 * ABUF_HALF * 2, stream);
  prep_a0<<<dim3((B_ * D_ + 255) / 256), dim3(256), 0, stream>>>(x, tm, abuf);
  lstm_persist<<<dim3(NBLK), dim3(NTHR), SMEM_BYTES, stream>>>(
      x, tm, Wx, bx, Wh, bh, out, abuf, flags, gen);
}